// Round 6
// baseline (1074.200 us; speedup 1.0000x reference)
//
#include <hip/hip_runtime.h>

#define N_NODES 10000
#define KMAX    128
#define GMB     79          // ceil(10000/128)
#define GRID_T  512         // persistent-tail grid: 2 blocks/CU x 256 CUs (guaranteed resident)

typedef __attribute__((ext_vector_type(8))) short short8v;
typedef __attribute__((ext_vector_type(4))) float f32x4;

// ---- bf16 helpers ----------------------------------------------------------
__device__ inline unsigned short f2bf(float f) {
    unsigned int u = __float_as_uint(f);
    return (unsigned short)((u + 0x7fffu + ((u >> 16) & 1u)) >> 16);
}
__device__ inline float bflo(unsigned int u) { return __uint_as_float(u << 16); }
__device__ inline float bfhi(unsigned int u) { return __uint_as_float(u & 0xffff0000u); }

struct Prm {
    const float *x, *adj, *alpha, *rzw, *w1, *rw1, *b1, *w2, *rw2, *b2, *w3, *rw3, *b3;
    int *cnt;                 // [N_NODES] edge counters, +bar at cnt[N_NODES]
    int *bar;                 // grid-barrier counter (monotonic)
    int *rowlen;
    float *dis, *invn;
    int *ell;
    unsigned short *aggxb, *cat1b, *cat2b, *h2b, *Pb, *rzwT, *w1T, *w2T, *w3T;
    float *out;
};

// ---------------------------------------------------------------------------
// Manual grid barrier (monotonic counter, agent scope). All GRID_T blocks are
// co-resident by construction, so this cannot deadlock. Same mechanism as
// cooperative groups' software grid.sync, without the coop-launch API.
// ---------------------------------------------------------------------------
__device__ inline void gbar(int* bar, int target)
{
    __syncthreads();
    if (threadIdx.x == 0) {
        __threadfence();   // make this block's writes visible device-wide
        __hip_atomic_fetch_add(bar, 1, __ATOMIC_ACQ_REL, __HIP_MEMORY_SCOPE_AGENT);
        while (__hip_atomic_load(bar, __ATOMIC_ACQUIRE, __HIP_MEMORY_SCOPE_AGENT) < target)
            __builtin_amdgcn_s_sleep(1);
        __threadfence();   // pull other blocks' writes before we proceed
    }
    __syncthreads();
}

// ---------------------------------------------------------------------------
// LDS-free aggregation: per-row group of tpr=C/2 threads; ell/dis loads are
// group-uniform (broadcast), h gathers coalesced. f32 acc, bf16 packed out.
// ---------------------------------------------------------------------------
__device__ void aggB(const unsigned short* __restrict__ hb, int hstride, int C,
                     unsigned short* __restrict__ outB, int ostride, int mean,
                     const Prm& p, int bid, int G)
{
    const int tpr = C >> 1;
    const int grp = 256 / tpr;
    const int sub = threadIdx.x / tpr;
    const int ln  = threadIdx.x - sub * tpr;
    for (int row = bid * grp + sub; row < N_NODES; row += G * grp) {
        int len = p.rowlen[row];
        const int* el = p.ell + (size_t)row * KMAX;
        float a0 = 0.0f, a1 = 0.0f;
        #pragma unroll 4
        for (int e = 0; e < len; ++e) {
            int j = el[e];
            float w = p.dis[j];
            unsigned int u = *reinterpret_cast<const unsigned int*>(
                hb + (size_t)j * hstride + 2 * ln);
            a0 += w * bflo(u);
            a1 += w * bfhi(u);
        }
        float s = mean ? p.dis[row] * p.invn[row] : p.dis[row];
        unsigned int pk = (unsigned int)f2bf(a0 * s) | ((unsigned int)f2bf(a1 * s) << 16);
        *reinterpret_cast<unsigned int*>(outB + (size_t)row * ostride + 2 * ln) = pk;
    }
}

// ---------------------------------------------------------------------------
// Final L3 aggregation: out[row,0:40] += dis_i*invn_i * sum_j dis_j*Pb[j,:]
// ---------------------------------------------------------------------------
__device__ void agg40(const Prm& p, int bid, int G)
{
    const int sub = threadIdx.x >> 5;
    const int ln  = threadIdx.x & 31;
    for (int row = bid * 8 + sub; row < N_NODES; row += G * 8) {
        if (ln < 20) {
            int len = p.rowlen[row];
            const int* el = p.ell + (size_t)row * KMAX;
            float a0 = 0.0f, a1 = 0.0f;
            #pragma unroll 4
            for (int e = 0; e < len; ++e) {
                int j = el[e];
                float w = p.dis[j];
                unsigned int u = *reinterpret_cast<const unsigned int*>(
                    p.Pb + (size_t)j * 40 + 2 * ln);
                a0 += w * bflo(u);
                a1 += w * bfhi(u);
            }
            float s = p.dis[row] * p.invn[row];
            size_t o = (size_t)row * 40 + 2 * ln;
            p.out[o]     += a0 * s;
            p.out[o + 1] += a1 * s;
        }
    }
}

// ---------------------------------------------------------------------------
// Grid-strided MFMA GEMM: C = A[10000 x K] @ BT[CoPad][K]^T. 128x128 tiles,
// 4 waves of 64x64, BK=32.
// modes: 0 = (+bias)(+relu) bf16 out; 1 = rezero (x + av*acc) bf16 out;
//        2 = col<40 -> Pb bf16, 40<=col<80 -> outQ f32 + bias[col-40]
// ---------------------------------------------------------------------------
__device__ void gemmT(const unsigned short* __restrict__ A, int lda, int K,
                      const unsigned short* __restrict__ BT, int Co,
                      const float* __restrict__ bias, int relu, int mode,
                      float av, const float* __restrict__ addend,
                      unsigned short* __restrict__ outB, int ostride, int ooff,
                      unsigned short* __restrict__ Pb, float* __restrict__ outQ,
                      int bid, int G,
                      unsigned short (*As)[40], unsigned short (*Bs)[40])
{
    const int M = N_NODES;
    const int tid  = threadIdx.x;
    const int lane = tid & 63;
    const int wid  = tid >> 6;
    const int wr   = wid >> 1, wc = wid & 1;
    const int fr   = lane & 15, fg = lane >> 4;
    const int nbn    = (Co + 127) >> 7;
    const int ntiles = GMB * nbn;

    for (int t = bid; t < ntiles; t += G) {
        const int bm = (t % GMB) * 128;
        const int bn = (t / GMB) * 128;
        f32x4 acc[4][4] = {};

        for (int k0 = 0; k0 < K; k0 += 32) {
            #pragma unroll
            for (int pp = 0; pp < 2; ++pp) {
                int i = tid + pp * 256;
                int r = i >> 2, kc = (i & 3) * 8;
                int arow = bm + r;
                uint4 v = make_uint4(0u, 0u, 0u, 0u);
                if (arow < M)
                    v = *reinterpret_cast<const uint4*>(A + (size_t)arow * lda + k0 + kc);
                *reinterpret_cast<uint4*>(&As[r][kc]) = v;
            }
            #pragma unroll
            for (int pp = 0; pp < 2; ++pp) {
                int i = tid + pp * 256;
                int c = i >> 2, kc = (i & 3) * 8;
                uint4 v = *reinterpret_cast<const uint4*>(BT + (size_t)(bn + c) * K + k0 + kc);
                *reinterpret_cast<uint4*>(&Bs[c][kc]) = v;
            }
            __syncthreads();

            short8v af[4], bf[4];
            #pragma unroll
            for (int m = 0; m < 4; ++m)
                af[m] = *reinterpret_cast<const short8v*>(&As[wr * 64 + m * 16 + fr][fg * 8]);
            #pragma unroll
            for (int n = 0; n < 4; ++n)
                bf[n] = *reinterpret_cast<const short8v*>(&Bs[wc * 64 + n * 16 + fr][fg * 8]);
            #pragma unroll
            for (int m = 0; m < 4; ++m)
                #pragma unroll
                for (int n = 0; n < 4; ++n)
                    acc[m][n] = __builtin_amdgcn_mfma_f32_16x16x32_bf16(af[m], bf[n], acc[m][n], 0, 0, 0);
            __syncthreads();
        }

        // C/D layout: col = lane&15, row = 4*(lane>>4)+reg  [HW-verified]
        #pragma unroll
        for (int m = 0; m < 4; ++m) {
            #pragma unroll
            for (int n = 0; n < 4; ++n) {
                int col = bn + wc * 64 + n * 16 + fr;
                if (col >= Co) continue;
                #pragma unroll
                for (int r = 0; r < 4; ++r) {
                    int row = bm + wr * 64 + m * 16 + fg * 4 + r;
                    if (row >= M) continue;
                    float v = acc[m][n][r];
                    if (mode == 0) {
                        if (bias) v += bias[col];
                        if (relu) v = fmaxf(v, 0.0f);
                        outB[(size_t)row * ostride + ooff + col] = f2bf(v);
                    } else if (mode == 1) {
                        v = addend[(size_t)row * 128 + col] + av * v;
                        outB[(size_t)row * ostride + ooff + col] = f2bf(v);
                    } else {
                        if (col < 40)      Pb[(size_t)row * 40 + col] = f2bf(v);
                        else if (col < 80) outQ[(size_t)row * 40 + (col - 40)] = v + bias[col - 40];
                    }
                }
            }
        }
    }
}

// ---------------------------------------------------------------------------
// Kernel 1: prep — x -> bf16 (cat1 h-half), weights -> bf16 [n][k], cnt/bar=0
// ---------------------------------------------------------------------------
__global__ void prep(Prm p)
{
    int i = blockIdx.x * 256 + threadIdx.x;
    if (i < 640000) {
        float2 v = reinterpret_cast<const float2*>(p.x)[i];
        unsigned int pk = (unsigned int)f2bf(v.x) | ((unsigned int)f2bf(v.y) << 16);
        int row = i >> 6, c = (i & 63) * 2;
        *reinterpret_cast<unsigned int*>(p.cat1b + (size_t)row * 256 + 128 + c) = pk;
        return;
    }
    i -= 640000;
    if (i < 16384) { int n = i >> 7, k = i & 127; p.rzwT[i] = f2bf(p.rzw[k * 128 + n]); return; }
    i -= 16384;
    if (i < 65536) {
        int n = i >> 8, k = i & 255;
        p.w1T[i] = f2bf((k < 128) ? p.w1[k * 256 + n] : p.rw1[(k - 128) * 256 + n]);
        return;
    }
    i -= 65536;
    if (i < 131072) {
        int n = i >> 9, k = i & 511;
        p.w2T[i] = f2bf((k < 256) ? p.w2[k * 256 + n] : p.rw2[(k - 256) * 256 + n]);
        return;
    }
    i -= 131072;
    if (i < 32768) {
        int n = i >> 8, k = i & 255;
        float v = 0.0f;
        if (n < 40)      v = p.w3[k * 40 + n];
        else if (n < 80) v = p.rw3[k * 40 + (n - 40)];
        p.w3T[i] = f2bf(v);
        return;
    }
    i -= 32768;
    if (i < N_NODES + 8) p.cnt[i] = 0;   // counters + barrier word
}

// ---------------------------------------------------------------------------
// Kernel 2: symmetric half-scan (200 MB), full-occupancy HBM stream.
// ---------------------------------------------------------------------------
__global__ __launch_bounds__(256) void build_sym(Prm p)
{
    int row = blockIdx.x;
    const float4* rp = reinterpret_cast<const float4*>(p.adj + (size_t)row * N_NODES);
    for (int f = (row >> 2) + threadIdx.x; f < N_NODES / 4; f += 256) {
        float4 v = rp[f];
        int base = f * 4;
        #pragma unroll
        for (int s = 0; s < 4; ++s) {
            float e = (s == 0) ? v.x : (s == 1) ? v.y : (s == 2) ? v.z : v.w;
            int j = base + s;
            if (e != 0.0f && j >= row) {
                int q = atomicAdd(&p.cnt[row], 1);
                if (q < KMAX) p.ell[(size_t)row * KMAX + q] = j;
                if (j > row) {
                    int q2 = atomicAdd(&p.cnt[j], 1);
                    if (q2 < KMAX) p.ell[(size_t)j * KMAX + q2] = row;
                }
            }
        }
    }
}

// ---------------------------------------------------------------------------
// Kernel 3: persistent tail — deg stats + rezero + 3 layers, manual barriers.
// 512 blocks x 256 threads, 2 blocks/CU guaranteed resident.
// ---------------------------------------------------------------------------
__global__ __launch_bounds__(256, 2) void tail(Prm p)
{
    const int bid = blockIdx.x;
    const int tid = threadIdx.x;
    __shared__ unsigned short As[128][40];
    __shared__ unsigned short Bs[128][40];
    int ph = 0;

    // P0: degree stats from counters
    for (int i = bid * 256 + tid; i < N_NODES; i += GRID_T * 256) {
        int d = p.cnt[i]; if (d > KMAX) d = KMAX; if (d < 1) d = 1;
        p.rowlen[i] = d;
        float fd = (float)d;
        p.dis[i]  = rsqrtf(fd);
        p.invn[i] = 1.0f / fd;
    }
    gbar(p.bar, (++ph) * GRID_T);

    // P1: rezero branch (grid-uniform gate; alpha==0 -> h0 = x already staged)
    float av = p.alpha[0];
    if (av != 0.0f) {
        aggB(p.cat1b + 128, 256, 128, p.aggxb, 128, 0, p, bid, GRID_T);
        gbar(p.bar, (++ph) * GRID_T);
        gemmT(p.aggxb, 128, 128, p.rzwT, 128, nullptr, 0, 1, av, p.x,
              p.cat1b, 256, 128, nullptr, nullptr, bid, GRID_T, As, Bs);
        gbar(p.bar, (++ph) * GRID_T);
    }

    // P2: agg1 -> cat1[:,0:128]
    aggB(p.cat1b + 128, 256, 128, p.cat1b, 256, 1, p, bid, GRID_T);
    gbar(p.bar, (++ph) * GRID_T);
    // P3: gemm1 -> cat2[:,256:512] (relu)
    gemmT(p.cat1b, 256, 256, p.w1T, 256, p.b1, 1, 0, 0.0f, nullptr,
          p.cat2b, 512, 256, nullptr, nullptr, bid, GRID_T, As, Bs);
    gbar(p.bar, (++ph) * GRID_T);
    // P4: agg2 -> cat2[:,0:256]
    aggB(p.cat2b + 256, 512, 256, p.cat2b, 512, 1, p, bid, GRID_T);
    gbar(p.bar, (++ph) * GRID_T);
    // P5: gemm2 -> h2b (relu)
    gemmT(p.cat2b, 512, 512, p.w2T, 256, p.b2, 1, 0, 0.0f, nullptr,
          p.h2b, 256, 0, nullptr, nullptr, bid, GRID_T, As, Bs);
    gbar(p.bar, (++ph) * GRID_T);
    // P6: gemm3 -> Pb (h2@w3) and out = h2@rw3 + b3
    gemmT(p.h2b, 256, 256, p.w3T, 80, p.b3, 0, 2, 0.0f, nullptr,
          nullptr, 0, 0, p.Pb, p.out, bid, GRID_T, As, Bs);
    gbar(p.bar, (++ph) * GRID_T);
    // P7: out += Dm * Ahat * Pb
    agg40(p, bid, GRID_T);
}

extern "C" void kernel_launch(void* const* d_in, const int* in_sizes, int n_in,
                              void* d_out, int out_size, void* d_ws, size_t ws_size,
                              hipStream_t stream)
{
    (void)in_sizes; (void)n_in; (void)out_size; (void)ws_size;
    char* ws = (char*)d_ws;
    size_t off = 0;
    auto alloc = [&](size_t bytes) -> char* {
        char* q = ws + off;
        off = (off + bytes + 255) & ~(size_t)255;
        return q;
    };

    Prm p;
    p.x     = (const float*)d_in[0];
    p.adj   = (const float*)d_in[1];
    p.alpha = (const float*)d_in[2];
    p.rzw   = (const float*)d_in[3];
    p.w1    = (const float*)d_in[4];
    p.rw1   = (const float*)d_in[5];
    p.b1    = (const float*)d_in[6];
    p.w2    = (const float*)d_in[7];
    p.rw2   = (const float*)d_in[8];
    p.b2    = (const float*)d_in[9];
    p.w3    = (const float*)d_in[10];
    p.rw3   = (const float*)d_in[11];
    p.b3    = (const float*)d_in[12];
    p.out   = (float*)d_out;

    p.cnt    = (int*)  alloc((size_t)(N_NODES + 8) * 4);
    p.bar    = p.cnt + N_NODES;
    p.rowlen = (int*)  alloc((size_t)N_NODES * 4);
    p.dis    = (float*)alloc((size_t)N_NODES * 4);
    p.invn   = (float*)alloc((size_t)N_NODES * 4);
    p.ell    = (int*)  alloc((size_t)N_NODES * KMAX * 4);
    p.aggxb  = (unsigned short*)alloc((size_t)N_NODES * 128 * 2);
    p.cat1b  = (unsigned short*)alloc((size_t)N_NODES * 256 * 2);
    p.cat2b  = (unsigned short*)alloc((size_t)N_NODES * 512 * 2);
    p.h2b    = (unsigned short*)alloc((size_t)N_NODES * 256 * 2);
    p.Pb     = (unsigned short*)alloc((size_t)N_NODES * 40 * 2);
    p.rzwT   = (unsigned short*)alloc((size_t)128 * 128 * 2);
    p.w1T    = (unsigned short*)alloc((size_t)256 * 256 * 2);
    p.w2T    = (unsigned short*)alloc((size_t)256 * 512 * 2);
    p.w3T    = (unsigned short*)alloc((size_t)128 * 256 * 2);

    prep<<<(640000 + 245760 + N_NODES + 8 + 255) / 256, 256, 0, stream>>>(p);
    build_sym<<<N_NODES, 256, 0, stream>>>(p);
    tail<<<GRID_T, 256, 0, stream>>>(p);
}

// Round 7
// 147.138 us; speedup vs baseline: 7.3006x; 7.3006x over previous
//
#include <hip/hip_runtime.h>

#define N_NODES 10000
#define KMAX    128
#define GMB     79                       // ceil(10000/128)
#define PREP_TOT (640000 + 16384 + 65536 + 131072 + 32768)   // = 885760 = 3460*256

typedef __attribute__((ext_vector_type(8))) short short8v;
typedef __attribute__((ext_vector_type(4))) float f32x4;

// ---- bf16 helpers ----------------------------------------------------------
__device__ inline unsigned short f2bf(float f) {
    unsigned int u = __float_as_uint(f);
    return (unsigned short)((u + 0x7fffu + ((u >> 16) & 1u)) >> 16);
}
__device__ inline float bflo(unsigned int u) { return __uint_as_float(u << 16); }
__device__ inline float bfhi(unsigned int u) { return __uint_as_float(u & 0xffff0000u); }

struct Prm {
    const float *x, *rzw, *w1, *rw1, *w2, *rw2, *w3, *rw3;
    unsigned short *cat1b, *rzwT, *w1T, *w2T, *w3T;
};

// ---------------------------------------------------------------------------
// Fused prep + symmetric half-scan.
// Prologue: blocks 0..3459 convert one prep element per thread
//   (x -> bf16 into cat1[:,128:256]; weights -> bf16 [n][k] with concat/merge).
// Body: block = row, scan cols j >= row (200 MB total), emit edges both ways
//   via global atomic cursors (cnt pre-zeroed by hipMemsetAsync).
// ---------------------------------------------------------------------------
__global__ __launch_bounds__(256) void prep_scan(
    Prm p, const float* __restrict__ adj, int* __restrict__ ell, int* __restrict__ cnt)
{
    int gi = blockIdx.x * 256 + threadIdx.x;
    if (gi < PREP_TOT) {
        int i = gi;
        if (i < 640000) {
            float2 v = reinterpret_cast<const float2*>(p.x)[i];
            unsigned int pk = (unsigned int)f2bf(v.x) | ((unsigned int)f2bf(v.y) << 16);
            int row = i >> 6, c = (i & 63) * 2;
            *reinterpret_cast<unsigned int*>(p.cat1b + (size_t)row * 256 + 128 + c) = pk;
            goto scan;
        }
        i -= 640000;
        if (i < 16384) { int n = i >> 7, k = i & 127; p.rzwT[i] = f2bf(p.rzw[k * 128 + n]); goto scan; }
        i -= 16384;
        if (i < 65536) {
            int n = i >> 8, k = i & 255;
            p.w1T[i] = f2bf((k < 128) ? p.w1[k * 256 + n] : p.rw1[(k - 128) * 256 + n]);
            goto scan;
        }
        i -= 65536;
        if (i < 131072) {
            int n = i >> 9, k = i & 511;
            p.w2T[i] = f2bf((k < 256) ? p.w2[k * 256 + n] : p.rw2[(k - 256) * 256 + n]);
            goto scan;
        }
        i -= 131072;
        {
            int n = i >> 8, k = i & 255;
            float v = 0.0f;
            if (n < 40)      v = p.w3[k * 40 + n];
            else if (n < 80) v = p.rw3[k * 40 + (n - 40)];
            p.w3T[i] = f2bf(v);
        }
    }
scan:
    {
        int row = blockIdx.x;
        const float4* rp = reinterpret_cast<const float4*>(adj + (size_t)row * N_NODES);
        for (int f = (row >> 2) + threadIdx.x; f < N_NODES / 4; f += 256) {
            float4 v = rp[f];
            int base = f * 4;
            #pragma unroll
            for (int s = 0; s < 4; ++s) {
                float e = (s == 0) ? v.x : (s == 1) ? v.y : (s == 2) ? v.z : v.w;
                int j = base + s;
                if (e != 0.0f && j >= row) {
                    int q = atomicAdd(&cnt[row], 1);
                    if (q < KMAX) ell[(size_t)row * KMAX + q] = j;
                    if (j > row) {
                        int q2 = atomicAdd(&cnt[j], 1);
                        if (q2 < KMAX) ell[(size_t)j * KMAX + q2] = row;
                    }
                }
            }
        }
    }
}

// ---------------------------------------------------------------------------
// Sparse aggregation over bf16 rows (f32 accumulate), bf16 packed output.
// Degree scales computed inline from cnt (deg == nnz, binary adj).
// gate != null: early-out when gate[0] == 0 (rezero branch, alpha==0).
// ---------------------------------------------------------------------------
__global__ void agg_b(
    const unsigned short* __restrict__ hb, int hstride,
    const int* __restrict__ ell, const int* __restrict__ cnt,
    unsigned short* __restrict__ outB, int ostride, int mean_flag,
    const float* __restrict__ gate)
{
    if (gate && gate[0] == 0.0f) return;
    int row = blockIdx.x;
    __shared__ int   sj[KMAX];
    __shared__ float sw[KMAX];
    int len = cnt[row]; if (len > KMAX) len = KMAX; if (len < 1) len = 1;
    for (int e = threadIdx.x; e < len; e += blockDim.x) {
        int j = ell[(size_t)row * KMAX + e];
        sj[e] = j;
        int d = cnt[j]; if (d > KMAX) d = KMAX; if (d < 1) d = 1;
        sw[e] = rsqrtf((float)d);
    }
    __syncthreads();
    int t = threadIdx.x;
    float a0 = 0.0f, a1 = 0.0f;
    #pragma unroll 4
    for (int e = 0; e < len; ++e) {
        unsigned int u = *reinterpret_cast<const unsigned int*>(
            hb + (size_t)sj[e] * hstride + 2 * t);
        float w = sw[e];
        a0 += w * bflo(u);
        a1 += w * bfhi(u);
    }
    float fd = (float)len;
    float s = mean_flag ? rsqrtf(fd) / fd : rsqrtf(fd);
    unsigned int pk = (unsigned int)f2bf(a0 * s) | ((unsigned int)f2bf(a1 * s) << 16);
    *reinterpret_cast<unsigned int*>(outB + (size_t)row * ostride + 2 * t) = pk;
}

// ---------------------------------------------------------------------------
// Final L3 aggregation: out[row,0:40] += deg^-1.5 * sum_j dis_j * Pb[j,:]
// ---------------------------------------------------------------------------
__global__ void agg_add40(
    const unsigned short* __restrict__ Pb,
    const int* __restrict__ ell, const int* __restrict__ cnt,
    float* __restrict__ out)
{
    int row = blockIdx.x;
    __shared__ int   sj[KMAX];
    __shared__ float sw[KMAX];
    int len = cnt[row]; if (len > KMAX) len = KMAX; if (len < 1) len = 1;
    for (int e = threadIdx.x; e < len; e += blockDim.x) {
        int j = ell[(size_t)row * KMAX + e];
        sj[e] = j;
        int d = cnt[j]; if (d > KMAX) d = KMAX; if (d < 1) d = 1;
        sw[e] = rsqrtf((float)d);
    }
    __syncthreads();
    int t = threadIdx.x;
    if (t < 20) {
        float a0 = 0.0f, a1 = 0.0f;
        #pragma unroll 4
        for (int e = 0; e < len; ++e) {
            unsigned int u = *reinterpret_cast<const unsigned int*>(
                Pb + (size_t)sj[e] * 40 + 2 * t);
            float w = sw[e];
            a0 += w * bflo(u);
            a1 += w * bfhi(u);
        }
        float fd = (float)len;
        float s = rsqrtf(fd) / fd;
        size_t o = (size_t)row * 40 + 2 * t;
        out[o]     += a0 * s;
        out[o + 1] += a1 * s;
    }
}

// ---------------------------------------------------------------------------
// bf16 MFMA GEMM: C = A[M x K] @ BT[CoPad][K]^T. 128x64 block tile
// (grid = (79, Co/64)), 4 waves of 32x64 rows, BK=32.
// modes: 0 = (+bias)(+relu) bf16 out; 1 = rezero (addend + alpha*acc) bf16,
//        early-out when alpha==0; 2 = col<40 -> Pb bf16, 40<=col<80 -> outQ f32.
// ---------------------------------------------------------------------------
__global__ __launch_bounds__(256) void gemm_mfma(
    const unsigned short* __restrict__ A, int M, int lda, int K,
    const unsigned short* __restrict__ BT,
    int Co, const float* __restrict__ bias, int relu_flag, int mode,
    const float* __restrict__ alpha_ptr, const float* __restrict__ addend,
    unsigned short* __restrict__ outB, int ostride, int ooff,
    unsigned short* __restrict__ Pb, float* __restrict__ outQ)
{
    if (mode == 1 && alpha_ptr[0] == 0.0f) return;  // h-half already holds x
    __shared__ unsigned short As[128][40];   // +8 pad: 2-way bank alias (free)
    __shared__ unsigned short Bs[64][40];
    const int tid  = threadIdx.x;
    const int lane = tid & 63;
    const int wid  = tid >> 6;                   // wave -> rows [wid*32, wid*32+32)
    const int fr   = lane & 15, fg = lane >> 4;
    const int bm   = blockIdx.x * 128;
    const int bn   = blockIdx.y * 64;

    f32x4 acc[2][4] = {};

    for (int k0 = 0; k0 < K; k0 += 32) {
        #pragma unroll
        for (int pp = 0; pp < 2; ++pp) {
            int i = tid + pp * 256;
            int r = i >> 2, kc = (i & 3) * 8;
            int arow = bm + r;
            uint4 v = make_uint4(0u, 0u, 0u, 0u);
            if (arow < M)
                v = *reinterpret_cast<const uint4*>(A + (size_t)arow * lda + k0 + kc);
            *reinterpret_cast<uint4*>(&As[r][kc]) = v;
        }
        {
            int c = tid >> 2, kc = (tid & 3) * 8;
            uint4 v = *reinterpret_cast<const uint4*>(BT + (size_t)(bn + c) * K + k0 + kc);
            *reinterpret_cast<uint4*>(&Bs[c][kc]) = v;
        }
        __syncthreads();

        short8v af[2], bf[4];
        #pragma unroll
        for (int m = 0; m < 2; ++m)
            af[m] = *reinterpret_cast<const short8v*>(&As[wid * 32 + m * 16 + fr][fg * 8]);
        #pragma unroll
        for (int n = 0; n < 4; ++n)
            bf[n] = *reinterpret_cast<const short8v*>(&Bs[n * 16 + fr][fg * 8]);
        #pragma unroll
        for (int m = 0; m < 2; ++m)
            #pragma unroll
            for (int n = 0; n < 4; ++n)
                acc[m][n] = __builtin_amdgcn_mfma_f32_16x16x32_bf16(af[m], bf[n], acc[m][n], 0, 0, 0);
        __syncthreads();
    }

    // C/D layout: col = lane&15, row = 4*(lane>>4)+reg  [HW-verified]
    #pragma unroll
    for (int m = 0; m < 2; ++m) {
        #pragma unroll
        for (int n = 0; n < 4; ++n) {
            int col = bn + n * 16 + fr;
            if (col >= Co) continue;
            #pragma unroll
            for (int r = 0; r < 4; ++r) {
                int row = bm + wid * 32 + m * 16 + fg * 4 + r;
                if (row >= M) continue;
                float v = acc[m][n][r];
                if (mode == 0) {
                    if (bias) v += bias[col];
                    if (relu_flag) v = fmaxf(v, 0.0f);
                    outB[(size_t)row * ostride + ooff + col] = f2bf(v);
                } else if (mode == 1) {
                    v = addend[(size_t)row * 128 + col] + alpha_ptr[0] * v;
                    outB[(size_t)row * ostride + ooff + col] = f2bf(v);
                } else {
                    if (col < 40)      Pb[(size_t)row * 40 + col] = f2bf(v);
                    else if (col < 80) outQ[(size_t)row * 40 + (col - 40)] = v + bias[col - 40];
                }
            }
        }
    }
}

extern "C" void kernel_launch(void* const* d_in, const int* in_sizes, int n_in,
                              void* d_out, int out_size, void* d_ws, size_t ws_size,
                              hipStream_t stream)
{
    (void)in_sizes; (void)n_in; (void)out_size; (void)ws_size;
    const float* x     = (const float*)d_in[0];
    const float* adj   = (const float*)d_in[1];
    const float* alpha = (const float*)d_in[2];
    const float* b1    = (const float*)d_in[6];
    const float* b2    = (const float*)d_in[9];
    const float* b3    = (const float*)d_in[12];
    float* out = (float*)d_out;

    char* ws = (char*)d_ws;
    size_t off = 0;
    auto alloc = [&](size_t bytes) -> char* {
        char* q = ws + off;
        off = (off + bytes + 255) & ~(size_t)255;
        return q;
    };
    int*            cnt    = (int*)  alloc((size_t)N_NODES * 4);
    int*            ell    = (int*)  alloc((size_t)N_NODES * KMAX * 4);
    unsigned short* aggxb  = (unsigned short*)alloc((size_t)N_NODES * 128 * 2);
    unsigned short* cat1b  = (unsigned short*)alloc((size_t)N_NODES * 256 * 2); // [agg|h0]
    unsigned short* cat2b  = (unsigned short*)alloc((size_t)N_NODES * 512 * 2); // [agg|h1]
    unsigned short* h2b    = (unsigned short*)alloc((size_t)N_NODES * 256 * 2);
    unsigned short* Pb     = (unsigned short*)alloc((size_t)N_NODES * 40 * 2);
    unsigned short* rzwT   = (unsigned short*)alloc((size_t)128 * 128 * 2);
    unsigned short* w1T    = (unsigned short*)alloc((size_t)256 * 256 * 2);
    unsigned short* w2T    = (unsigned short*)alloc((size_t)256 * 512 * 2);
    unsigned short* w3T    = (unsigned short*)alloc((size_t)128 * 256 * 2);

    Prm p;
    p.x = x; p.rzw = (const float*)d_in[3];
    p.w1 = (const float*)d_in[4]; p.rw1 = (const float*)d_in[5];
    p.w2 = (const float*)d_in[7]; p.rw2 = (const float*)d_in[8];
    p.w3 = (const float*)d_in[10]; p.rw3 = (const float*)d_in[11];
    p.cat1b = cat1b; p.rzwT = rzwT; p.w1T = w1T; p.w2T = w2T; p.w3T = w3T;

    // zero edge counters, then fused prep + 200 MB half-scan
    hipMemsetAsync(cnt, 0, (size_t)N_NODES * 4, stream);
    prep_scan<<<N_NODES, 256, 0, stream>>>(p, adj, ell, cnt);

    // rezero branch (both gated on alpha==0; h0 = x already staged by prep)
    agg_b<<<N_NODES, 64, 0, stream>>>(cat1b + 128, 256, ell, cnt, aggxb, 128, 0, alpha);
    gemm_mfma<<<dim3(GMB, 2), 256, 0, stream>>>(aggxb, N_NODES, 128, 128, rzwT,
                                                128, nullptr, 0, 1, alpha, x,
                                                cat1b, 256, 128, nullptr, nullptr);

    // layer 1: agg -> cat1[:,0:128]; h1 = relu(cat1@[w1;rw1]+b1) -> cat2[:,256:512]
    agg_b<<<N_NODES, 64, 0, stream>>>(cat1b + 128, 256, ell, cnt, cat1b, 256, 1, nullptr);
    gemm_mfma<<<dim3(GMB, 4), 256, 0, stream>>>(cat1b, N_NODES, 256, 256, w1T,
                                                256, b1, 1, 0, nullptr, nullptr,
                                                cat2b, 512, 256, nullptr, nullptr);

    // layer 2: agg -> cat2[:,0:256]; h2 = relu(cat2@[w2;rw2]+b2) -> h2b
    agg_b<<<N_NODES, 128, 0, stream>>>(cat2b + 256, 512, ell, cnt, cat2b, 512, 1, nullptr);
    gemm_mfma<<<dim3(GMB, 4), 256, 0, stream>>>(cat2b, N_NODES, 512, 512, w2T,
                                                256, b2, 1, 0, nullptr, nullptr,
                                                h2b, 256, 0, nullptr, nullptr);

    // layer 3 (reordered): P = h2@w3 -> Pb, out = h2@rw3 + b3; out += Dm·Â·P
    gemm_mfma<<<dim3(GMB, 2), 256, 0, stream>>>(h2b, N_NODES, 256, 256, w3T,
                                                80, b3, 0, 2, nullptr, nullptr,
                                                nullptr, 0, 0, Pb, out);
    agg_add40<<<N_NODES, 64, 0, stream>>>(Pb, ell, cnt, out);
}